// Round 1
// baseline (1085.732 us; speedup 1.0000x reference)
//
#include <hip/hip_runtime.h>
#include <cstdint>
#include <cstddef>

#define Kn 32
#define Bn 512
#define Tn 2048
#define START 30
#define STOP 31
#define NEGV -10000.0f
#define LN2F 0.69314718055994530942f

// broadcast within each 32-lane segment: all lanes get s from lane (seg_base + idx)
__device__ __forceinline__ float bcast32(float v, int idx) {
  return __shfl(v, idx, 32);
}

// one CRF forward step in exp domain.
// lane layout: n = lane&31 (next state), hb = 16*(lane>>5) (base of this lane's prev half)
// er[j] = exp(trans[n][hb+j]); s holds exp-domain alpha for state n (replicated across halves)
__device__ __forceinline__ float crf_step(float s, float eemit,
                                          const float (&er)[16], int hb) {
  float a0 = 0.f, a1 = 0.f, a2 = 0.f, a3 = 0.f;
#pragma unroll
  for (int j = 0; j < 4; ++j) {
    a0 = fmaf(bcast32(s, hb + j),      er[j],      a0);
    a1 = fmaf(bcast32(s, hb + 4 + j),  er[4 + j],  a1);
    a2 = fmaf(bcast32(s, hb + 8 + j),  er[8 + j],  a2);
    a3 = fmaf(bcast32(s, hb + 12 + j), er[12 + j], a3);
  }
  float p = (a0 + a1) + (a2 + a3);     // partial over this lane's 16 prevs
  p += __shfl_xor(p, 32);              // combine the two prev-halves
  return p * eemit;
}

// exact power-of-two renormalization; returns updated log-offset
__device__ __forceinline__ float renorm(float& s, float off) {
  int e = (int)((__float_as_uint(s) >> 23) & 255u);
  e = max(e, __shfl_xor(e, 1));
  e = max(e, __shfl_xor(e, 2));
  e = max(e, __shfl_xor(e, 4));
  e = max(e, __shfl_xor(e, 8));
  e = max(e, __shfl_xor(e, 16));       // both halves hold same state set -> 32-wide max is global
  s *= __uint_as_float((unsigned)(254 - e) << 23);  // * 2^(127-emax), exact
  return off + (float)(e - 127) * LN2F;
}

__global__ __launch_bounds__(64, 1) void crf_main(
    const float* __restrict__ feats, const float* __restrict__ trans,
    const int* __restrict__ tags, const int* __restrict__ lens,
    float* __restrict__ fscore, float* __restrict__ gold) {
  const int lane = threadIdx.x;

  if (blockIdx.x < Bn) {
    // ---------------- forward algorithm (log-partition), exp domain ----------------
    const int b = blockIdx.x;
    const int n = lane & 31;
    const int hb = (lane >> 5) * 16;

    float er[16], estop[16];
#pragma unroll
    for (int j = 0; j < 16; ++j) {
      er[j]    = __expf(trans[n * Kn + hb + j]);       // exp(NEG) == 0 exactly
      estop[j] = __expf(trans[STOP * Kn + hb + j]);
    }

    const int len = lens[b];
    const float* fbase = feats + ((size_t)b * Tn) * Kn + n;  // stride Kn per step

    float s = (n == START) ? 1.0f : 0.0f;  // exp(init alpha); exp(-10000) ~ 0
    float off = 0.0f;

    // register ring prefetch, depth 8 (static indexing only — no scratch)
    float fbuf[8];
#pragma unroll
    for (int i = 0; i < 8; ++i) fbuf[i] = fbase[(size_t)i * Kn];

    int t = 0;
    const int nm = len >> 3;
    for (int m = 0; m < nm; ++m) {
#pragma unroll
      for (int i = 0; i < 8; ++i) {
        const float f = fbuf[i];
        const int tp = t + i + 8;
        if (tp < Tn) fbuf[i] = fbase[(size_t)tp * Kn];  // uniform branch
        s = crf_step(s, __expf(f), er, hb);
        if ((i & 3) == 3) off = renorm(s, off);
      }
      t += 8;
    }
    // tail: <8 steps; emissions are already L1-hot from prefetch
    const int rem = len & 7;
    for (int i = 0; i < rem; ++i) {
      const float f = fbase[(size_t)(t + i) * Kn];
      s = crf_step(s, __expf(f), er, hb);
      off = renorm(s, off);
    }

    // forward_score = log(sum_p s[p] * exp(trans[STOP][p])) + off
    float a0 = 0.f, a1 = 0.f, a2 = 0.f, a3 = 0.f;
#pragma unroll
    for (int j = 0; j < 4; ++j) {
      a0 = fmaf(bcast32(s, hb + j),      estop[j],      a0);
      a1 = fmaf(bcast32(s, hb + 4 + j),  estop[4 + j],  a1);
      a2 = fmaf(bcast32(s, hb + 8 + j),  estop[8 + j],  a2);
      a3 = fmaf(bcast32(s, hb + 12 + j), estop[12 + j], a3);
    }
    float p = (a0 + a1) + (a2 + a3);
    p += __shfl_xor(p, 32);
    if (lane == 0) fscore[b] = __logf(p) + off;
  } else {
    // ---------------- gold-path score ----------------
    const int b = blockIdx.x - Bn;
    const int len = lens[b];
    const int* tg = tags + (size_t)b * Tn;
    const float* fb = feats + (size_t)b * Tn * Kn;
    float acc = 0.f;
    for (int tt = lane; tt < len; tt += 64) {
      const int tag = tg[tt];
      const int prev = (tt == 0) ? START : tg[tt - 1];
      acc += fb[(size_t)tt * Kn + tag] + trans[tag * Kn + prev];
    }
    if (lane == 0) acc += trans[STOP * Kn + tg[len - 1]];
#pragma unroll
    for (int msk = 32; msk >= 1; msk >>= 1) acc += __shfl_xor(acc, msk);
    if (lane == 0) gold[b] = acc;
  }
}

__global__ __launch_bounds__(64, 1) void crf_reduce(
    const float* __restrict__ fscore, const float* __restrict__ gold,
    float* __restrict__ out) {
  const int lane = threadIdx.x;
  float acc = 0.f;
  for (int i = lane; i < Bn; i += 64) acc += fscore[i] - gold[i];
#pragma unroll
  for (int msk = 32; msk >= 1; msk >>= 1) acc += __shfl_xor(acc, msk);
  if (lane == 0) out[0] = acc * (1.0f / (float)Bn);
}

extern "C" void kernel_launch(void* const* d_in, const int* in_sizes, int n_in,
                              void* d_out, int out_size, void* d_ws, size_t ws_size,
                              hipStream_t stream) {
  const float* feats = (const float*)d_in[0];
  const float* trans = (const float*)d_in[1];
  const int*   tags  = (const int*)d_in[2];
  const int*   lens  = (const int*)d_in[3];
  float* fscore = (float*)d_ws;        // [Bn]
  float* gold   = fscore + Bn;         // [Bn]
  crf_main<<<2 * Bn, 64, 0, stream>>>(feats, trans, tags, lens, fscore, gold);
  crf_reduce<<<1, 64, 0, stream>>>(fscore, gold, (float*)d_out);
}

// Round 2
// 362.235 us; speedup vs baseline: 2.9973x; 2.9973x over previous
//
#include <hip/hip_runtime.h>
#include <hip/hip_bf16.h>
#include <cstdint>
#include <cstddef>

#define Kn 32
#define Bn 512
#define Tn 2048
#define CH 128            // chunk length (Tn/CH chunks per batch elem)
#define NC (Tn / CH)      // 16
#define START 30
#define STOP 31
#define LN2F 0.69314718055994530942f

typedef __attribute__((ext_vector_type(8))) short bf16x8;   // 8 bf16 (4 VGPRs)
typedef __attribute__((ext_vector_type(16))) float f32x16;  // MFMA 32x32 accum

union BF8 { bf16x8 v; unsigned u[4]; };

// pack two f32 -> packed bf16 pair (RNE via HIP intrinsic; low = first)
__device__ __forceinline__ unsigned pk2(float lo, float hi) {
  union { __hip_bfloat162 h; unsigned u; } r;
  r.h = __float22bfloat162_rn(make_float2(lo, hi));
  return r.u;
}

__device__ __forceinline__ float bcast32(float v, int idx) {
  return __shfl(v, idx, 32);
}

// ---------------------------------------------------------------------------
// Phase 1: per-(batch, chunk) transfer-matrix product via MFMA.
// P_new = M_t * P_old ; A = M_t (row-scaled exp(trans), 2^-7 static rescale),
// B = P_old. D layout (measured): row=(r&3)+8*(r>>2)+4h, col=lane&31.
// A layout: A[m][k], m=lane&31, k=8h+j. B layout: B[k][n], n=lane&31, k=8h+j.
// ---------------------------------------------------------------------------
__device__ __forceinline__ void crf_mm_step(
    float f, const float (&e1)[8], const float (&e2)[8],
    unsigned (&b1u)[4], unsigned (&b2u)[4], int h,
    float& off, bool rn, const f32x16& zf, f32x16& acc) {
  const float w = __expf(f) * 0.0078125f;  // exp(feat[m]) * 2^-7 (static renorm)
  BF8 A1, A2, B1, B2;
#pragma unroll
  for (int j = 0; j < 4; ++j) {
    A1.u[j] = pk2(e1[2 * j] * w, e1[2 * j + 1] * w);
    A2.u[j] = pk2(e2[2 * j] * w, e2[2 * j + 1] * w);
    B1.u[j] = b1u[j];
    B2.u[j] = b2u[j];
  }
  acc = __builtin_amdgcn_mfma_f32_32x32x16_bf16(A2.v, B2.v, zf, 0, 0, 0);
  acc = __builtin_amdgcn_mfma_f32_32x32x16_bf16(A1.v, B1.v, acc, 0, 0, 0);

  if (rn) {  // exact power-of-2 renorm (every 32 steps)
    float mx = acc[0];
#pragma unroll
    for (int r = 1; r < 16; ++r) mx = fmaxf(mx, acc[r]);
#pragma unroll
    for (int d = 1; d < 64; d <<= 1) mx = fmaxf(mx, __shfl_xor(mx, d));
    const int e = (int)((__float_as_uint(mx) >> 23) & 255u);
    const float sc = __uint_as_float((unsigned)(254 - e) << 23);
#pragma unroll
    for (int r = 0; r < 16; ++r) acc[r] *= sc;
    off += (float)(e - 127) * LN2F;
  }

  // D (f32) -> B fragments (bf16) for the next step.
  // q[i] packs D regs (2i,2i+1) = rows: q0=(0,1) q1=(2,3) q2=(8,9) q3=(10,11)
  // q4=(16,17) q5=(18,19) q6=(24,25) q7=(26,27), all +4h.
  unsigned q[8];
#pragma unroll
  for (int i = 0; i < 8; ++i) q[i] = pk2(acc[2 * i], acc[2 * i + 1]);
  // cross-half exchange: h=0 needs rows (4,5),(6,7),(20,21),(22,23) from h=1;
  // h=1 needs (8,9),(10,11),(24,25),(26,27) from h=0.
  const unsigned r1 = __shfl_xor(h ? q[0] : q[2], 32);
  const unsigned r2 = __shfl_xor(h ? q[1] : q[3], 32);
  const unsigned r3 = __shfl_xor(h ? q[4] : q[6], 32);
  const unsigned r4 = __shfl_xor(h ? q[5] : q[7], 32);
  b1u[0] = h ? r1 : q[0];
  b1u[1] = h ? r2 : q[1];
  b1u[2] = h ? q[2] : r1;
  b1u[3] = h ? q[3] : r2;
  b2u[0] = h ? r3 : q[4];
  b2u[1] = h ? r4 : q[5];
  b2u[2] = h ? q[6] : r3;
  b2u[3] = h ? q[7] : r4;
}

__global__ __launch_bounds__(64, 4) void crf_chunks(
    const float* __restrict__ feats, const float* __restrict__ trans,
    const int* __restrict__ lens, float* __restrict__ pmats,
    float* __restrict__ poffs) {
  const int bc = blockIdx.x;
  const int b = bc >> 4, c = bc & (NC - 1);
  const int len = lens[b];
  const int t0 = c * CH;
  if (t0 >= len) return;                       // pure-identity chunk: skipped
  const int nsteps = min(t0 + CH, len) - t0;   // identity tail handled by stopping
  const int lane = threadIdx.x;
  const int m = lane & 31;
  const int h = lane >> 5;

  // constant A-side fragments of exp(trans): E[m][8h+j] and E[m][16+8h+j]
  float e1[8], e2[8];
  {
    const float* tr = trans + m * Kn + 8 * h;
#pragma unroll
    for (int j = 0; j < 8; ++j) {
      e1[j] = __expf(tr[j]);        // exp(-10000) == 0 exactly
      e2[j] = __expf(tr[16 + j]);
    }
  }

  // running product as B fragments, init = Identity (bf16 1.0 = 0x3F80)
  unsigned b1u[4] = {0u, 0u, 0u, 0u}, b2u[4] = {0u, 0u, 0u, 0u};
  {
    int j = m - 8 * h;
    if (0 <= j && j < 8) b1u[j >> 1] |= (j & 1) ? 0x3F800000u : 0x00003F80u;
    j = m - 16 - 8 * h;
    if (0 <= j && j < 8) b2u[j >> 1] |= (j & 1) ? 0x3F800000u : 0x00003F80u;
  }

  f32x16 zf = {0.f, 0.f, 0.f, 0.f, 0.f, 0.f, 0.f, 0.f,
               0.f, 0.f, 0.f, 0.f, 0.f, 0.f, 0.f, 0.f};
  f32x16 acc;
  float off = 0.0f;
  const float* fb = feats + ((size_t)b * Tn + t0) * Kn + m;

  float ring[8];
#pragma unroll
  for (int i = 0; i < 8; ++i) ring[i] = fb[(size_t)i * Kn];

  int t = 0;
  const int nb = nsteps >> 3;
  for (int mb = 0; mb < nb; ++mb) {
    const bool rnblk = ((mb & 3) == 3);
#pragma unroll
    for (int i = 0; i < 8; ++i) {
      const float f = ring[i];
      const int tp = t + i + 8;
      if (t0 + tp < Tn) ring[i] = fb[(size_t)tp * Kn];  // uniform branch
      crf_mm_step(f, e1, e2, b1u, b2u, h, off, rnblk && (i == 7), zf, acc);
    }
    t += 8;
  }
  const int rem = nsteps & 7;
  for (int i = 0; i < rem; ++i) {
    const float f = fb[(size_t)(t + i) * Kn];
    crf_mm_step(f, e1, e2, b1u, b2u, h, off, false, zf, acc);
  }

  // store chunk product (f32, row-major) + log offset
  float* pm = pmats + (size_t)bc * (Kn * Kn);
#pragma unroll
  for (int r = 0; r < 16; ++r) {
    const int row = (r & 3) + 8 * (r >> 2) + 4 * h;
    pm[row * Kn + m] = acc[r];
  }
  if (lane == 0) poffs[bc] = off + 7.0f * LN2F * (float)nsteps;
}

// ---------------------------------------------------------------------------
// Phase 2: apply <=16 chunk matrices serially per batch elem (+ gold score).
// ---------------------------------------------------------------------------
__device__ __forceinline__ float renorm_s(float& s, float off) {
  int e = (int)((__float_as_uint(s) >> 23) & 255u);
  e = max(e, __shfl_xor(e, 1));
  e = max(e, __shfl_xor(e, 2));
  e = max(e, __shfl_xor(e, 4));
  e = max(e, __shfl_xor(e, 8));
  e = max(e, __shfl_xor(e, 16));
  s *= __uint_as_float((unsigned)(254 - e) << 23);
  return off + (float)(e - 127) * LN2F;
}

__global__ __launch_bounds__(64, 1) void crf_apply(
    const float* __restrict__ feats, const float* __restrict__ trans,
    const int* __restrict__ tags, const int* __restrict__ lens,
    const float* __restrict__ pmats, const float* __restrict__ poffs,
    float* __restrict__ fscore, float* __restrict__ gold) {
  const int lane = threadIdx.x;
  if (blockIdx.x < Bn) {
    const int b = blockIdx.x;
    const int n = lane & 31;
    const int hb = (lane >> 5) * 16;
    const int len = lens[b];
    const int nc = (len + CH - 1) / CH;
    float s = (n == START) ? 1.0f : 0.0f;
    float off = 0.0f;
    for (int c = 0; c < nc; ++c) {
      const float* pm = pmats + (size_t)(b * NC + c) * (Kn * Kn) + n * Kn + hb;
      const float4 p0 = *(const float4*)pm;
      const float4 p1 = *(const float4*)(pm + 4);
      const float4 p2 = *(const float4*)(pm + 8);
      const float4 p3 = *(const float4*)(pm + 12);
      float a0 = 0.f, a1 = 0.f, a2 = 0.f, a3 = 0.f;
      a0 = fmaf(bcast32(s, hb + 0), p0.x, a0);
      a0 = fmaf(bcast32(s, hb + 1), p0.y, a0);
      a0 = fmaf(bcast32(s, hb + 2), p0.z, a0);
      a0 = fmaf(bcast32(s, hb + 3), p0.w, a0);
      a1 = fmaf(bcast32(s, hb + 4), p1.x, a1);
      a1 = fmaf(bcast32(s, hb + 5), p1.y, a1);
      a1 = fmaf(bcast32(s, hb + 6), p1.z, a1);
      a1 = fmaf(bcast32(s, hb + 7), p1.w, a1);
      a2 = fmaf(bcast32(s, hb + 8), p2.x, a2);
      a2 = fmaf(bcast32(s, hb + 9), p2.y, a2);
      a2 = fmaf(bcast32(s, hb + 10), p2.z, a2);
      a2 = fmaf(bcast32(s, hb + 11), p2.w, a2);
      a3 = fmaf(bcast32(s, hb + 12), p3.x, a3);
      a3 = fmaf(bcast32(s, hb + 13), p3.y, a3);
      a3 = fmaf(bcast32(s, hb + 14), p3.z, a3);
      a3 = fmaf(bcast32(s, hb + 15), p3.w, a3);
      float p = (a0 + a1) + (a2 + a3);
      p += __shfl_xor(p, 32);
      s = p;
      off = renorm_s(s, off);
      off += poffs[b * NC + c];
    }
    const float es = __expf(trans[STOP * Kn + n]);
    float q = s * es;
#pragma unroll
    for (int d = 1; d < 32; d <<= 1) q += __shfl_xor(q, d);
    if (lane == 0) fscore[b] = __logf(q) + off;
  } else {
    const int b = blockIdx.x - Bn;
    const int len = lens[b];
    const int* tg = tags + (size_t)b * Tn;
    const float* fbp = feats + (size_t)b * Tn * Kn;
    float acc = 0.f;
    for (int tt = lane; tt < len; tt += 64) {
      const int tag = tg[tt];
      const int prev = (tt == 0) ? START : tg[tt - 1];
      acc += fbp[(size_t)tt * Kn + tag] + trans[tag * Kn + prev];
    }
    if (lane == 0) acc += trans[STOP * Kn + tg[len - 1]];
#pragma unroll
    for (int msk = 32; msk >= 1; msk >>= 1) acc += __shfl_xor(acc, msk);
    if (lane == 0) gold[b] = acc;
  }
}

// ---------------------------------------------------------------------------
// Fallback (round-1 serial kernel) if ws too small for chunk matrices.
// ---------------------------------------------------------------------------
__device__ __forceinline__ float crf_step_slow(float s, float eemit,
                                               const float (&er)[16], int hb) {
  float a0 = 0.f, a1 = 0.f, a2 = 0.f, a3 = 0.f;
#pragma unroll
  for (int j = 0; j < 4; ++j) {
    a0 = fmaf(bcast32(s, hb + j), er[j], a0);
    a1 = fmaf(bcast32(s, hb + 4 + j), er[4 + j], a1);
    a2 = fmaf(bcast32(s, hb + 8 + j), er[8 + j], a2);
    a3 = fmaf(bcast32(s, hb + 12 + j), er[12 + j], a3);
  }
  float p = (a0 + a1) + (a2 + a3);
  p += __shfl_xor(p, 32);
  return p * eemit;
}

__global__ __launch_bounds__(64, 1) void crf_main(
    const float* __restrict__ feats, const float* __restrict__ trans,
    const int* __restrict__ tags, const int* __restrict__ lens,
    float* __restrict__ fscore, float* __restrict__ gold) {
  const int lane = threadIdx.x;
  if (blockIdx.x < Bn) {
    const int b = blockIdx.x;
    const int n = lane & 31;
    const int hb = (lane >> 5) * 16;
    float er[16], estop[16];
#pragma unroll
    for (int j = 0; j < 16; ++j) {
      er[j] = __expf(trans[n * Kn + hb + j]);
      estop[j] = __expf(trans[STOP * Kn + hb + j]);
    }
    const int len = lens[b];
    const float* fbase = feats + ((size_t)b * Tn) * Kn + n;
    float s = (n == START) ? 1.0f : 0.0f;
    float off = 0.0f;
    float fbuf[8];
#pragma unroll
    for (int i = 0; i < 8; ++i) fbuf[i] = fbase[(size_t)i * Kn];
    int t = 0;
    const int nm = len >> 3;
    for (int m2 = 0; m2 < nm; ++m2) {
#pragma unroll
      for (int i = 0; i < 8; ++i) {
        const float f = fbuf[i];
        const int tp = t + i + 8;
        if (tp < Tn) fbuf[i] = fbase[(size_t)tp * Kn];
        s = crf_step_slow(s, __expf(f), er, hb);
        if ((i & 3) == 3) off = renorm_s(s, off);
      }
      t += 8;
    }
    const int rem = len & 7;
    for (int i = 0; i < rem; ++i) {
      const float f = fbase[(size_t)(t + i) * Kn];
      s = crf_step_slow(s, __expf(f), er, hb);
      off = renorm_s(s, off);
    }
    float a0 = 0.f, a1 = 0.f, a2 = 0.f, a3 = 0.f;
#pragma unroll
    for (int j = 0; j < 4; ++j) {
      a0 = fmaf(bcast32(s, hb + j), estop[j], a0);
      a1 = fmaf(bcast32(s, hb + 4 + j), estop[4 + j], a1);
      a2 = fmaf(bcast32(s, hb + 8 + j), estop[8 + j], a2);
      a3 = fmaf(bcast32(s, hb + 12 + j), estop[12 + j], a3);
    }
    float p = (a0 + a1) + (a2 + a3);
    p += __shfl_xor(p, 32);
    if (lane == 0) fscore[b] = __logf(p) + off;
  } else {
    const int b = blockIdx.x - Bn;
    const int len = lens[b];
    const int* tg = tags + (size_t)b * Tn;
    const float* fb = feats + (size_t)b * Tn * Kn;
    float acc = 0.f;
    for (int tt = lane; tt < len; tt += 64) {
      const int tag = tg[tt];
      const int prev = (tt == 0) ? START : tg[tt - 1];
      acc += fb[(size_t)tt * Kn + tag] + trans[tag * Kn + prev];
    }
    if (lane == 0) acc += trans[STOP * Kn + tg[len - 1]];
#pragma unroll
    for (int msk = 32; msk >= 1; msk >>= 1) acc += __shfl_xor(acc, msk);
    if (lane == 0) gold[b] = acc;
  }
}

__global__ __launch_bounds__(64, 1) void crf_reduce(
    const float* __restrict__ fscore, const float* __restrict__ gold,
    float* __restrict__ out) {
  const int lane = threadIdx.x;
  float acc = 0.f;
  for (int i = lane; i < Bn; i += 64) acc += fscore[i] - gold[i];
#pragma unroll
  for (int msk = 32; msk >= 1; msk >>= 1) acc += __shfl_xor(acc, msk);
  if (lane == 0) out[0] = acc * (1.0f / (float)Bn);
}

extern "C" void kernel_launch(void* const* d_in, const int* in_sizes, int n_in,
                              void* d_out, int out_size, void* d_ws, size_t ws_size,
                              hipStream_t stream) {
  const float* feats = (const float*)d_in[0];
  const float* trans = (const float*)d_in[1];
  const int* tags = (const int*)d_in[2];
  const int* lens = (const int*)d_in[3];

  float* fscore = (float*)d_ws;             // [Bn]
  float* gold = fscore + Bn;                // [Bn]
  const size_t need =
      ((size_t)Bn * NC * Kn * Kn + (size_t)Bn * NC + 2 * Bn) * sizeof(float);
  if (ws_size >= need) {
    float* poffs = gold + Bn;               // [Bn*NC]
    float* pmats = poffs + (size_t)Bn * NC; // [Bn*NC*1024]
    crf_chunks<<<Bn * NC, 64, 0, stream>>>(feats, trans, lens, pmats, poffs);
    crf_apply<<<2 * Bn, 64, 0, stream>>>(feats, trans, tags, lens, pmats, poffs,
                                         fscore, gold);
  } else {
    crf_main<<<2 * Bn, 64, 0, stream>>>(feats, trans, tags, lens, fscore, gold);
  }
  crf_reduce<<<1, 64, 0, stream>>>(fscore, gold, (float*)d_out);
}

// Round 3
// 345.250 us; speedup vs baseline: 3.1448x; 1.0492x over previous
//
#include <hip/hip_runtime.h>
#include <hip/hip_bf16.h>
#include <cstdint>
#include <cstddef>

#define Kn 32
#define Bn 512
#define Tn 2048
#define CH 128            // chunk length
#define NC (Tn / CH)      // 16 chunks per batch row
#define GP 8              // gold partials per batch row
#define START 30
#define STOP 31
#define LN2F 0.69314718055994530942f

typedef __attribute__((ext_vector_type(8))) short bf16x8;   // 8 bf16 (4 VGPRs)
typedef __attribute__((ext_vector_type(16))) float f32x16;  // MFMA 32x32 accum

union BF8 { bf16x8 v; unsigned u[4]; };

__device__ __forceinline__ unsigned pk2(float lo, float hi) {
  union { __hip_bfloat162 h; unsigned u; } r;
  r.h = __float22bfloat162_rn(make_float2(lo, hi));
  return r.u;
}

__device__ __forceinline__ float bcast32(float v, int idx) {
  return __shfl(v, idx, 32);
}

// ---------------------------------------------------------------------------
// Fused phase 1: mm-blocks (2 chunk-product chains per wave) + gold partials.
// P_new = diag(exp(feat_t))*exp(trans) * P_old via 2x mfma_f32_32x32x16_bf16.
// D layout: row=(r&3)+8*(r>>2)+4h, col=lane&31. A: A[m][k], m=lane&31, k=8h+j.
// B: B[k][n], n=lane&31, k=8h+j.
// ---------------------------------------------------------------------------
__global__ __launch_bounds__(64, 4) void crf_fused(
    const float* __restrict__ feats, const float* __restrict__ trans,
    const int* __restrict__ tags, const int* __restrict__ lens,
    float* __restrict__ pmats, float* __restrict__ poffs,
    float* __restrict__ gold_part) {
  const int lane = threadIdx.x;

  if (blockIdx.x < (Bn / 2) * NC) {   // 4096 mm blocks
    const int bc = blockIdx.x;
    const int b = bc >> 3, c0 = bc & 7;     // chains: (b,c0) and (b,c0+8)
    const int len = lens[b];
    const int n1 = min(max(len - c0 * CH, 0), CH);
    const int n2 = min(max(len - (c0 + 8) * CH, 0), CH);   // n2 <= n1 always
    if (n1 == 0) return;

    const int m = lane & 31;
    const int h = lane >> 5;

    float e1[8], e2[8];
    {
      const float* tr = trans + m * Kn + 8 * h;
#pragma unroll
      for (int j = 0; j < 8; ++j) {
        e1[j] = __expf(tr[j]);        // exp(-10000) == 0 exactly
        e2[j] = __expf(tr[16 + j]);
      }
    }

    const f32x16 zf = {0.f, 0.f, 0.f, 0.f, 0.f, 0.f, 0.f, 0.f,
                       0.f, 0.f, 0.f, 0.f, 0.f, 0.f, 0.f, 0.f};

    // per-chain state
    unsigned c1b1[4] = {0, 0, 0, 0}, c1b2[4] = {0, 0, 0, 0};
    unsigned c2b1[4] = {0, 0, 0, 0}, c2b2[4] = {0, 0, 0, 0};
    {   // identity init (bf16 1.0 = 0x3F80)
      int j = m - 8 * h;
      unsigned v = (j & 1) ? 0x3F800000u : 0x00003F80u;
      if (0 <= j && j < 8) { c1b1[j >> 1] |= v; c2b1[j >> 1] |= v; }
      j = m - 16 - 8 * h;
      v = (j & 1) ? 0x3F800000u : 0x00003F80u;
      if (0 <= j && j < 8) { c1b2[j >> 1] |= v; c2b2[j >> 1] |= v; }
    }
    f32x16 acc1, acc2;
    float off1 = 0.f, off2 = 0.f;

    const int t01 = c0 * CH, t02 = (c0 + 8) * CH;
    const float* fb1 = feats + ((size_t)b * Tn + t01) * Kn + m;
    const float* fb2 = feats + ((size_t)b * Tn + t02) * Kn + m;
    const int lim1 = Tn - 1 - t01, lim2 = Tn - 1 - t02;  // clamp for prefetch

    float ring1[8], ring2[8];
#pragma unroll
    for (int i = 0; i < 8; ++i) {
      ring1[i] = fb1[(size_t)min(i, lim1) * Kn];
      ring2[i] = fb2[(size_t)min(i, lim2) * Kn];
    }

    auto mmstep = [&](float f, unsigned (&bu1)[4], unsigned (&bu2)[4],
                      f32x16& acc, float& off, bool rn) {
      const float w = __expf(f) * 0.0078125f;  // exp(feat) * 2^-7
      BF8 A1, A2, B1, B2;
#pragma unroll
      for (int j = 0; j < 4; ++j) {
        A1.u[j] = pk2(e1[2 * j] * w, e1[2 * j + 1] * w);
        A2.u[j] = pk2(e2[2 * j] * w, e2[2 * j + 1] * w);
        B1.u[j] = bu1[j];
        B2.u[j] = bu2[j];
      }
      acc = __builtin_amdgcn_mfma_f32_32x32x16_bf16(A2.v, B2.v, zf, 0, 0, 0);
      acc = __builtin_amdgcn_mfma_f32_32x32x16_bf16(A1.v, B1.v, acc, 0, 0, 0);

      if (rn) {  // exact power-of-2 renorm
        float mx = acc[0];
#pragma unroll
        for (int r = 1; r < 16; ++r) mx = fmaxf(mx, acc[r]);
#pragma unroll
        for (int d = 1; d < 64; d <<= 1) mx = fmaxf(mx, __shfl_xor(mx, d));
        const int e = (int)((__float_as_uint(mx) >> 23) & 255u);
        const float sc = __uint_as_float((unsigned)(254 - e) << 23);
#pragma unroll
        for (int r = 0; r < 16; ++r) acc[r] *= sc;
        off += (float)(e - 127) * LN2F;
      }

      unsigned q[8];
#pragma unroll
      for (int i = 0; i < 8; ++i) q[i] = pk2(acc[2 * i], acc[2 * i + 1]);
      const unsigned r1 = __shfl_xor(h ? q[0] : q[2], 32);
      const unsigned r2 = __shfl_xor(h ? q[1] : q[3], 32);
      const unsigned r3 = __shfl_xor(h ? q[4] : q[6], 32);
      const unsigned r4 = __shfl_xor(h ? q[5] : q[7], 32);
      bu1[0] = h ? r1 : q[0];
      bu1[1] = h ? r2 : q[1];
      bu1[2] = h ? q[2] : r1;
      bu1[3] = h ? q[3] : r2;
      bu2[0] = h ? r3 : q[4];
      bu2[1] = h ? r4 : q[5];
      bu2[2] = h ? q[6] : r3;
      bu2[3] = h ? q[7] : r4;
    };

    int t = 0;
    const int nb = n1 >> 3;
    for (int mb = 0; mb < nb; ++mb) {
#pragma unroll
      for (int i = 0; i < 8; ++i) {
        const int tt = t + i;
        const bool rn = ((tt & 31) == 31);
        {
          const float f = ring1[i];
          ring1[i] = fb1[(size_t)min(tt + 8, lim1) * Kn];
          mmstep(f, c1b1, c1b2, acc1, off1, rn);
        }
        if (tt < n2) {   // wave-uniform guard
          const float f = ring2[i];
          ring2[i] = fb2[(size_t)min(tt + 8, lim2) * Kn];
          mmstep(f, c2b1, c2b2, acc2, off2, rn);
        }
      }
      t += 8;
    }
    const int rem = n1 & 7;
    for (int i = 0; i < rem; ++i) {
      const int tt = t + i;
      mmstep(ring1[i], c1b1, c1b2, acc1, off1, false);
      if (tt < n2) mmstep(ring2[i], c2b1, c2b2, acc2, off2, false);
    }

    // store chunk products (f32 row-major) + log offsets
    {
      float* pm = pmats + (size_t)(b * NC + c0) * (Kn * Kn);
#pragma unroll
      for (int r = 0; r < 16; ++r) {
        const int row = (r & 3) + 8 * (r >> 2) + 4 * h;
        pm[row * Kn + m] = acc1[r];
      }
      if (lane == 0) poffs[b * NC + c0] = off1 + 7.0f * LN2F * (float)n1;
    }
    if (n2 > 0) {
      float* pm = pmats + (size_t)(b * NC + c0 + 8) * (Kn * Kn);
#pragma unroll
      for (int r = 0; r < 16; ++r) {
        const int row = (r & 3) + 8 * (r >> 2) + 4 * h;
        pm[row * Kn + m] = acc2[r];
      }
      if (lane == 0) poffs[b * NC + c0 + 8] = off2 + 7.0f * LN2F * (float)n2;
    }
  } else {
    // ------------------- gold partial sums (8 spans of 256 per b) ----------
    const int g = blockIdx.x - (Bn / 2) * NC;
    const int b = g >> 3, p = g & 7;
    const int len = lens[b];
    const int t0 = p * 256;
    const int t1 = min(t0 + 256, len);
    const int* tg = tags + (size_t)b * Tn;
    const float* fbp = feats + (size_t)b * Tn * Kn;
    float acc = 0.f;
    for (int tt = t0 + lane; tt < t1; tt += 64) {
      const int tag = tg[tt];
      const int prev = tt ? tg[tt - 1] : START;
      acc += fbp[(size_t)tt * Kn + tag] + trans[tag * Kn + prev];
    }
    if (lane == 0 && ((len - 1) >> 8) == p)
      acc += trans[STOP * Kn + tg[len - 1]];
#pragma unroll
    for (int msk = 32; msk >= 1; msk >>= 1) acc += __shfl_xor(acc, msk);
    if (lane == 0) gold_part[b * GP + p] = acc;   // always written (0 if idle)
  }
}

// ---------------------------------------------------------------------------
// Phase 2: apply <=16 chunk matrices serially per batch elem.
// ---------------------------------------------------------------------------
__device__ __forceinline__ float renorm_s(float& s, float off) {
  int e = (int)((__float_as_uint(s) >> 23) & 255u);
  e = max(e, __shfl_xor(e, 1));
  e = max(e, __shfl_xor(e, 2));
  e = max(e, __shfl_xor(e, 4));
  e = max(e, __shfl_xor(e, 8));
  e = max(e, __shfl_xor(e, 16));
  s *= __uint_as_float((unsigned)(254 - e) << 23);
  return off + (float)(e - 127) * LN2F;
}

__global__ __launch_bounds__(64, 1) void crf_apply(
    const float* __restrict__ trans, const int* __restrict__ lens,
    const float* __restrict__ pmats, const float* __restrict__ poffs,
    float* __restrict__ fscore) {
  const int lane = threadIdx.x;
  const int b = blockIdx.x;
  const int n = lane & 31;
  const int hb = (lane >> 5) * 16;
  const int len = lens[b];
  const int nc = (len + CH - 1) / CH;
  float s = (n == START) ? 1.0f : 0.0f;
  float off = 0.0f;
  for (int c = 0; c < nc; ++c) {
    const float* pm = pmats + (size_t)(b * NC + c) * (Kn * Kn) + n * Kn + hb;
    const float4 p0 = *(const float4*)pm;
    const float4 p1 = *(const float4*)(pm + 4);
    const float4 p2 = *(const float4*)(pm + 8);
    const float4 p3 = *(const float4*)(pm + 12);
    float a0 = 0.f, a1 = 0.f, a2 = 0.f, a3 = 0.f;
    a0 = fmaf(bcast32(s, hb + 0), p0.x, a0);
    a0 = fmaf(bcast32(s, hb + 1), p0.y, a0);
    a0 = fmaf(bcast32(s, hb + 2), p0.z, a0);
    a0 = fmaf(bcast32(s, hb + 3), p0.w, a0);
    a1 = fmaf(bcast32(s, hb + 4), p1.x, a1);
    a1 = fmaf(bcast32(s, hb + 5), p1.y, a1);
    a1 = fmaf(bcast32(s, hb + 6), p1.z, a1);
    a1 = fmaf(bcast32(s, hb + 7), p1.w, a1);
    a2 = fmaf(bcast32(s, hb + 8), p2.x, a2);
    a2 = fmaf(bcast32(s, hb + 9), p2.y, a2);
    a2 = fmaf(bcast32(s, hb + 10), p2.z, a2);
    a2 = fmaf(bcast32(s, hb + 11), p2.w, a2);
    a3 = fmaf(bcast32(s, hb + 12), p3.x, a3);
    a3 = fmaf(bcast32(s, hb + 13), p3.y, a3);
    a3 = fmaf(bcast32(s, hb + 14), p3.z, a3);
    a3 = fmaf(bcast32(s, hb + 15), p3.w, a3);
    float p = (a0 + a1) + (a2 + a3);
    p += __shfl_xor(p, 32);
    s = p;
    off = renorm_s(s, off);
    off += poffs[b * NC + c];
  }
  const float es = __expf(trans[STOP * Kn + n]);
  float q = s * es;
#pragma unroll
  for (int d = 1; d < 32; d <<= 1) q += __shfl_xor(q, d);
  if (lane == 0) fscore[b] = __logf(q) + off;
}

// ---------------------------------------------------------------------------
// Fallback (round-1 serial kernel) if ws too small for chunk matrices.
// ---------------------------------------------------------------------------
__device__ __forceinline__ float crf_step_slow(float s, float eemit,
                                               const float (&er)[16], int hb) {
  float a0 = 0.f, a1 = 0.f, a2 = 0.f, a3 = 0.f;
#pragma unroll
  for (int j = 0; j < 4; ++j) {
    a0 = fmaf(bcast32(s, hb + j), er[j], a0);
    a1 = fmaf(bcast32(s, hb + 4 + j), er[4 + j], a1);
    a2 = fmaf(bcast32(s, hb + 8 + j), er[8 + j], a2);
    a3 = fmaf(bcast32(s, hb + 12 + j), er[12 + j], a3);
  }
  float p = (a0 + a1) + (a2 + a3);
  p += __shfl_xor(p, 32);
  return p * eemit;
}

__global__ __launch_bounds__(64, 1) void crf_main(
    const float* __restrict__ feats, const float* __restrict__ trans,
    const int* __restrict__ tags, const int* __restrict__ lens,
    float* __restrict__ fscore, float* __restrict__ gold_part) {
  const int lane = threadIdx.x;
  if (blockIdx.x < Bn) {
    const int b = blockIdx.x;
    const int n = lane & 31;
    const int hb = (lane >> 5) * 16;
    float er[16], estop[16];
#pragma unroll
    for (int j = 0; j < 16; ++j) {
      er[j] = __expf(trans[n * Kn + hb + j]);
      estop[j] = __expf(trans[STOP * Kn + hb + j]);
    }
    const int len = lens[b];
    const float* fbase = feats + ((size_t)b * Tn) * Kn + n;
    float s = (n == START) ? 1.0f : 0.0f;
    float off = 0.0f;
    float fbuf[8];
#pragma unroll
    for (int i = 0; i < 8; ++i) fbuf[i] = fbase[(size_t)i * Kn];
    int t = 0;
    const int nm = len >> 3;
    for (int m2 = 0; m2 < nm; ++m2) {
#pragma unroll
      for (int i = 0; i < 8; ++i) {
        const float f = fbuf[i];
        const int tp = t + i + 8;
        if (tp < Tn) fbuf[i] = fbase[(size_t)tp * Kn];
        s = crf_step_slow(s, __expf(f), er, hb);
        if ((i & 3) == 3) off = renorm_s(s, off);
      }
      t += 8;
    }
    const int rem = len & 7;
    for (int i = 0; i < rem; ++i) {
      const float f = fbase[(size_t)(t + i) * Kn];
      s = crf_step_slow(s, __expf(f), er, hb);
      off = renorm_s(s, off);
    }
    float a0 = 0.f, a1 = 0.f, a2 = 0.f, a3 = 0.f;
#pragma unroll
    for (int j = 0; j < 4; ++j) {
      a0 = fmaf(bcast32(s, hb + j), estop[j], a0);
      a1 = fmaf(bcast32(s, hb + 4 + j), estop[4 + j], a1);
      a2 = fmaf(bcast32(s, hb + 8 + j), estop[8 + j], a2);
      a3 = fmaf(bcast32(s, hb + 12 + j), estop[12 + j], a3);
    }
    float p = (a0 + a1) + (a2 + a3);
    p += __shfl_xor(p, 32);
    if (lane == 0) fscore[b] = __logf(p) + off;
  } else {
    const int b = blockIdx.x - Bn;
    const int len = lens[b];
    const int* tg = tags + (size_t)b * Tn;
    const float* fb = feats + (size_t)b * Tn * Kn;
    float acc = 0.f;
    for (int tt = lane; tt < len; tt += 64) {
      const int tag = tg[tt];
      const int prev = (tt == 0) ? START : tg[tt - 1];
      acc += fb[(size_t)tt * Kn + tag] + trans[tag * Kn + prev];
    }
    if (lane == 0) acc += trans[STOP * Kn + tg[len - 1]];
#pragma unroll
    for (int msk = 32; msk >= 1; msk >>= 1) acc += __shfl_xor(acc, msk);
    if (lane == 0) gold_part[b * GP] = acc;
    else if (lane < GP) gold_part[b * GP + lane] = 0.f;
  }
}

__global__ __launch_bounds__(64, 1) void crf_reduce(
    const float* __restrict__ fscore, const float* __restrict__ gold_part,
    float* __restrict__ out) {
  const int lane = threadIdx.x;
  float acc = 0.f;
  for (int i = lane; i < Bn; i += 64) {
    float gp = 0.f;
#pragma unroll
    for (int p = 0; p < GP; ++p) gp += gold_part[i * GP + p];
    acc += fscore[i] - gp;
  }
#pragma unroll
  for (int msk = 32; msk >= 1; msk >>= 1) acc += __shfl_xor(acc, msk);
  if (lane == 0) out[0] = acc * (1.0f / (float)Bn);
}

extern "C" void kernel_launch(void* const* d_in, const int* in_sizes, int n_in,
                              void* d_out, int out_size, void* d_ws, size_t ws_size,
                              hipStream_t stream) {
  const float* feats = (const float*)d_in[0];
  const float* trans = (const float*)d_in[1];
  const int* tags = (const int*)d_in[2];
  const int* lens = (const int*)d_in[3];

  float* fscore = (float*)d_ws;                    // [Bn]
  float* gold_part = fscore + Bn;                  // [Bn*GP]
  float* poffs = gold_part + (size_t)Bn * GP;      // [Bn*NC]
  float* pmats = poffs + (size_t)Bn * NC;          // [Bn*NC*1024]
  const size_t need =
      ((size_t)Bn + (size_t)Bn * GP + (size_t)Bn * NC +
       (size_t)Bn * NC * Kn * Kn) * sizeof(float);
  if (ws_size >= need) {
    crf_fused<<<(Bn / 2) * NC + Bn * GP, 64, 0, stream>>>(
        feats, trans, tags, lens, pmats, poffs, gold_part);
    crf_apply<<<Bn, 64, 0, stream>>>(trans, lens, pmats, poffs, fscore);
  } else {
    crf_main<<<2 * Bn, 64, 0, stream>>>(feats, trans, tags, lens, fscore,
                                        gold_part);
  }
  crf_reduce<<<1, 64, 0, stream>>>(fscore, gold_part, (float*)d_out);
}

// Round 4
// 290.399 us; speedup vs baseline: 3.7388x; 1.1889x over previous
//
#include <hip/hip_runtime.h>
#include <hip/hip_bf16.h>
#include <cstdint>
#include <cstddef>

#define Kn 32
#define Bn 512
#define Tn 2048
#define CH 128            // chunk length
#define NC (Tn / CH)      // 16 chunks per batch row
#define GP 8              // gold partials per batch row
#define MMB (Bn * NC / 4) // 2048 mm blocks (4 waves each)
#define GB (Bn * GP / 4)  // 1024 gold blocks (4 waves each)
#define START 30
#define STOP 31
#define LN2F 0.69314718055994530942f

typedef __attribute__((ext_vector_type(8))) short bf16x8;   // 8 bf16 (4 VGPRs)
typedef __attribute__((ext_vector_type(16))) float f32x16;  // MFMA 32x32 accum

union BF8 { bf16x8 v; unsigned u[4]; };

// pack two non-negative f32 -> bf16x2, round-half-up == RN for positives.
// 3 insts: v_add_u32 x2 + v_perm_b32.
__device__ __forceinline__ unsigned pk2(float lo, float hi) {
  return __builtin_amdgcn_perm(__float_as_uint(hi) + 0x8000u,
                               __float_as_uint(lo) + 0x8000u, 0x07060302u);
}

__device__ __forceinline__ float bcast32(float v, int idx) {
  return __shfl(v, idx, 32);
}

// ---------------------------------------------------------------------------
// Fused phase 1: 8192 single-chain chunk-product waves + 4096 gold waves,
// packed 4 waves per 256-thread block for occupancy.
// P_new = diag(exp(feat_t))*exp(trans) * P_old via 2x mfma_f32_32x32x16_bf16.
// D layout: row=(r&3)+8*(r>>2)+4h, col=lane&31. A: A[m][k], m=lane&31, k=8h+j.
// B: B[k][n], n=lane&31, k=8h+j.
// ---------------------------------------------------------------------------
__global__ __launch_bounds__(256, 6) void crf_fused(
    const float* __restrict__ feats, const float* __restrict__ trans,
    const int* __restrict__ tags, const int* __restrict__ lens,
    float* __restrict__ pmats, float* __restrict__ poffs,
    float* __restrict__ gold_part) {
  const int wid = threadIdx.x >> 6;
  const int lane = threadIdx.x & 63;

  if (blockIdx.x < MMB) {
    const int idx = blockIdx.x * 4 + wid;   // 0..8191
    const int c = idx >> 9;                 // same c across the block's 4 waves
    const int b = idx & (Bn - 1);
    const int len = lens[b];
    const int nsteps = min(max(len - c * CH, 0), CH);
    if (nsteps == 0) return;                // chunk never read by crf_apply

    const int m = lane & 31;
    const int h = lane >> 5;

    // E rows with the 2^-7 static renorm folded in; exp(-10000) == 0 exactly.
    float e1[8], e2[8];
    {
      const float* tr = trans + m * Kn + 8 * h;
#pragma unroll
      for (int j = 0; j < 8; ++j) {
        e1[j] = __expf(tr[j]) * 0.0078125f;
        e2[j] = __expf(tr[16 + j]) * 0.0078125f;
      }
    }

    // running product as B fragments, init = Identity (bf16 1.0 = 0x3F80)
    unsigned b1u[4] = {0, 0, 0, 0}, b2u[4] = {0, 0, 0, 0};
    {
      int j = m - 8 * h;
      if (0 <= j && j < 8) b1u[j >> 1] |= (j & 1) ? 0x3F800000u : 0x00003F80u;
      j = m - 16 - 8 * h;
      if (0 <= j && j < 8) b2u[j >> 1] |= (j & 1) ? 0x3F800000u : 0x00003F80u;
    }

    const f32x16 zf = {0.f, 0.f, 0.f, 0.f, 0.f, 0.f, 0.f, 0.f,
                       0.f, 0.f, 0.f, 0.f, 0.f, 0.f, 0.f, 0.f};
    f32x16 acc;
    float off = 0.0f;

    const int t0 = c * CH;
    const float* fb = feats + ((size_t)b * Tn + t0) * Kn + m;
    const int lim = Tn - 1 - t0;            // clamp for prefetch

    float ring[8];
#pragma unroll
    for (int i = 0; i < 8; ++i) ring[i] = fb[(size_t)min(i, lim) * Kn];

    auto mmstep = [&](float f, bool rn) {
      const float w = __expf(f);
      BF8 A1, A2, B1, B2;
#pragma unroll
      for (int j = 0; j < 4; ++j) {
        A1.u[j] = pk2(e1[2 * j] * w, e1[2 * j + 1] * w);
        A2.u[j] = pk2(e2[2 * j] * w, e2[2 * j + 1] * w);
        B1.u[j] = b1u[j];
        B2.u[j] = b2u[j];
      }
      acc = __builtin_amdgcn_mfma_f32_32x32x16_bf16(A2.v, B2.v, zf, 0, 0, 0);
      acc = __builtin_amdgcn_mfma_f32_32x32x16_bf16(A1.v, B1.v, acc, 0, 0, 0);

      if (rn) {  // exact power-of-2 renorm
        float mx = acc[0];
#pragma unroll
        for (int r = 1; r < 16; ++r) mx = fmaxf(mx, acc[r]);
#pragma unroll
        for (int d = 1; d < 64; d <<= 1) mx = fmaxf(mx, __shfl_xor(mx, d));
        const int e = (int)((__float_as_uint(mx) >> 23) & 255u);
        const float sc = __uint_as_float((unsigned)(254 - e) << 23);
#pragma unroll
        for (int r = 0; r < 16; ++r) acc[r] *= sc;
        off += (float)(e - 127) * LN2F;
      }

      // D (f32) -> B fragments (bf16) for next step
      unsigned q[8];
#pragma unroll
      for (int i = 0; i < 8; ++i) q[i] = pk2(acc[2 * i], acc[2 * i + 1]);
      const unsigned r1 = __shfl_xor(h ? q[0] : q[2], 32);
      const unsigned r2 = __shfl_xor(h ? q[1] : q[3], 32);
      const unsigned r3 = __shfl_xor(h ? q[4] : q[6], 32);
      const unsigned r4 = __shfl_xor(h ? q[5] : q[7], 32);
      b1u[0] = h ? r1 : q[0];
      b1u[1] = h ? r2 : q[1];
      b1u[2] = h ? q[2] : r1;
      b1u[3] = h ? q[3] : r2;
      b2u[0] = h ? r3 : q[4];
      b2u[1] = h ? r4 : q[5];
      b2u[2] = h ? q[6] : r3;
      b2u[3] = h ? q[7] : r4;
    };

    int t = 0;
    const int nb = nsteps >> 3;
    for (int mb = 0; mb < nb; ++mb) {
#pragma unroll
      for (int i = 0; i < 8; ++i) {
        const float f = ring[i];
        ring[i] = fb[(size_t)min(t + i + 8, lim) * Kn];
        mmstep(f, ((t + i) & 31) == 31);
      }
      t += 8;
    }
    const int rem = nsteps & 7;
    for (int i = 0; i < rem; ++i) mmstep(ring[i], false);

    // store chunk product (f32, row-major) + log offset
    float* pm = pmats + (size_t)(b * NC + c) * (Kn * Kn);
#pragma unroll
    for (int r = 0; r < 16; ++r) {
      const int row = (r & 3) + 8 * (r >> 2) + 4 * h;
      pm[row * Kn + m] = acc[r];
    }
    if (lane == 0) poffs[b * NC + c] = off + 7.0f * LN2F * (float)nsteps;
  } else {
    // ------------------- gold partial sums (8 spans of 256 per b) ----------
    const int g = (blockIdx.x - MMB) * 4 + wid;   // 0..4095
    const int b = g >> 3, p = g & 7;
    const int len = lens[b];
    const int t0 = p * 256;
    const int t1 = min(t0 + 256, len);
    const int* tg = tags + (size_t)b * Tn;
    const float* fbp = feats + (size_t)b * Tn * Kn;
    float acc = 0.f;
    for (int tt = t0 + lane; tt < t1; tt += 64) {
      const int tag = tg[tt];
      const int prev = tt ? tg[tt - 1] : START;
      acc += fbp[(size_t)tt * Kn + tag] + trans[tag * Kn + prev];
    }
    if (lane == 0 && ((len - 1) >> 8) == p)
      acc += trans[STOP * Kn + tg[len - 1]];
#pragma unroll
    for (int msk = 32; msk >= 1; msk >>= 1) acc += __shfl_xor(acc, msk);
    if (lane == 0) gold_part[b * GP + p] = acc;   // always written (0 if idle)
  }
}

// ---------------------------------------------------------------------------
// Phase 2: apply <=16 chunk matrices serially per batch elem.
// ---------------------------------------------------------------------------
__device__ __forceinline__ float renorm_s(float& s, float off) {
  int e = (int)((__float_as_uint(s) >> 23) & 255u);
  e = max(e, __shfl_xor(e, 1));
  e = max(e, __shfl_xor(e, 2));
  e = max(e, __shfl_xor(e, 4));
  e = max(e, __shfl_xor(e, 8));
  e = max(e, __shfl_xor(e, 16));
  s *= __uint_as_float((unsigned)(254 - e) << 23);
  return off + (float)(e - 127) * LN2F;
}

__global__ __launch_bounds__(64, 1) void crf_apply(
    const float* __restrict__ trans, const int* __restrict__ lens,
    const float* __restrict__ pmats, const float* __restrict__ poffs,
    float* __restrict__ fscore) {
  const int lane = threadIdx.x;
  const int b = blockIdx.x;
  const int n = lane & 31;
  const int hb = (lane >> 5) * 16;
  const int len = lens[b];
  const int nc = (len + CH - 1) / CH;
  float s = (n == START) ? 1.0f : 0.0f;
  float off = 0.0f;
  for (int c = 0; c < nc; ++c) {
    const float* pm = pmats + (size_t)(b * NC + c) * (Kn * Kn) + n * Kn + hb;
    const float4 p0 = *(const float4*)pm;
    const float4 p1 = *(const float4*)(pm + 4);
    const float4 p2 = *(const float4*)(pm + 8);
    const float4 p3 = *(const float4*)(pm + 12);
    float a0 = 0.f, a1 = 0.f, a2 = 0.f, a3 = 0.f;
    a0 = fmaf(bcast32(s, hb + 0), p0.x, a0);
    a0 = fmaf(bcast32(s, hb + 1), p0.y, a0);
    a0 = fmaf(bcast32(s, hb + 2), p0.z, a0);
    a0 = fmaf(bcast32(s, hb + 3), p0.w, a0);
    a1 = fmaf(bcast32(s, hb + 4), p1.x, a1);
    a1 = fmaf(bcast32(s, hb + 5), p1.y, a1);
    a1 = fmaf(bcast32(s, hb + 6), p1.z, a1);
    a1 = fmaf(bcast32(s, hb + 7), p1.w, a1);
    a2 = fmaf(bcast32(s, hb + 8), p2.x, a2);
    a2 = fmaf(bcast32(s, hb + 9), p2.y, a2);
    a2 = fmaf(bcast32(s, hb + 10), p2.z, a2);
    a2 = fmaf(bcast32(s, hb + 11), p2.w, a2);
    a3 = fmaf(bcast32(s, hb + 12), p3.x, a3);
    a3 = fmaf(bcast32(s, hb + 13), p3.y, a3);
    a3 = fmaf(bcast32(s, hb + 14), p3.z, a3);
    a3 = fmaf(bcast32(s, hb + 15), p3.w, a3);
    float p = (a0 + a1) + (a2 + a3);
    p += __shfl_xor(p, 32);
    s = p;
    off = renorm_s(s, off);
    off += poffs[b * NC + c];
  }
  const float es = __expf(trans[STOP * Kn + n]);
  float q = s * es;
#pragma unroll
  for (int d = 1; d < 32; d <<= 1) q += __shfl_xor(q, d);
  if (lane == 0) fscore[b] = __logf(q) + off;
}

// ---------------------------------------------------------------------------
// Fallback (serial scan) if ws too small for chunk matrices.
// ---------------------------------------------------------------------------
__device__ __forceinline__ float crf_step_slow(float s, float eemit,
                                               const float (&er)[16], int hb) {
  float a0 = 0.f, a1 = 0.f, a2 = 0.f, a3 = 0.f;
#pragma unroll
  for (int j = 0; j < 4; ++j) {
    a0 = fmaf(bcast32(s, hb + j), er[j], a0);
    a1 = fmaf(bcast32(s, hb + 4 + j), er[4 + j], a1);
    a2 = fmaf(bcast32(s, hb + 8 + j), er[8 + j], a2);
    a3 = fmaf(bcast32(s, hb + 12 + j), er[12 + j], a3);
  }
  float p = (a0 + a1) + (a2 + a3);
  p += __shfl_xor(p, 32);
  return p * eemit;
}

__global__ __launch_bounds__(64, 1) void crf_main(
    const float* __restrict__ feats, const float* __restrict__ trans,
    const int* __restrict__ tags, const int* __restrict__ lens,
    float* __restrict__ fscore, float* __restrict__ gold_part) {
  const int lane = threadIdx.x;
  if (blockIdx.x < Bn) {
    const int b = blockIdx.x;
    const int n = lane & 31;
    const int hb = (lane >> 5) * 16;
    float er[16], estop[16];
#pragma unroll
    for (int j = 0; j < 16; ++j) {
      er[j] = __expf(trans[n * Kn + hb + j]);
      estop[j] = __expf(trans[STOP * Kn + hb + j]);
    }
    const int len = lens[b];
    const float* fbase = feats + ((size_t)b * Tn) * Kn + n;
    float s = (n == START) ? 1.0f : 0.0f;
    float off = 0.0f;
    float fbuf[8];
#pragma unroll
    for (int i = 0; i < 8; ++i) fbuf[i] = fbase[(size_t)i * Kn];
    int t = 0;
    const int nm = len >> 3;
    for (int m2 = 0; m2 < nm; ++m2) {
#pragma unroll
      for (int i = 0; i < 8; ++i) {
        const float f = fbuf[i];
        const int tp = t + i + 8;
        if (tp < Tn) fbuf[i] = fbase[(size_t)tp * Kn];
        s = crf_step_slow(s, __expf(f), er, hb);
        if ((i & 3) == 3) off = renorm_s(s, off);
      }
      t += 8;
    }
    const int rem = len & 7;
    for (int i = 0; i < rem; ++i) {
      const float f = fbase[(size_t)(t + i) * Kn];
      s = crf_step_slow(s, __expf(f), er, hb);
      off = renorm_s(s, off);
    }
    float a0 = 0.f, a1 = 0.f, a2 = 0.f, a3 = 0.f;
#pragma unroll
    for (int j = 0; j < 4; ++j) {
      a0 = fmaf(bcast32(s, hb + j), estop[j], a0);
      a1 = fmaf(bcast32(s, hb + 4 + j), estop[4 + j], a1);
      a2 = fmaf(bcast32(s, hb + 8 + j), estop[8 + j], a2);
      a3 = fmaf(bcast32(s, hb + 12 + j), estop[12 + j], a3);
    }
    float p = (a0 + a1) + (a2 + a3);
    p += __shfl_xor(p, 32);
    if (lane == 0) fscore[b] = __logf(p) + off;
  } else {
    const int b = blockIdx.x - Bn;
    const int len = lens[b];
    const int* tg = tags + (size_t)b * Tn;
    const float* fb = feats + (size_t)b * Tn * Kn;
    float acc = 0.f;
    for (int tt = lane; tt < len; tt += 64) {
      const int tag = tg[tt];
      const int prev = (tt == 0) ? START : tg[tt - 1];
      acc += fb[(size_t)tt * Kn + tag] + trans[tag * Kn + prev];
    }
    if (lane == 0) acc += trans[STOP * Kn + tg[len - 1]];
#pragma unroll
    for (int msk = 32; msk >= 1; msk >>= 1) acc += __shfl_xor(acc, msk);
    if (lane == 0) gold_part[b * GP] = acc;
    else if (lane < GP) gold_part[b * GP + lane] = 0.f;
  }
}

__global__ __launch_bounds__(64, 1) void crf_reduce(
    const float* __restrict__ fscore, const float* __restrict__ gold_part,
    float* __restrict__ out) {
  const int lane = threadIdx.x;
  float acc = 0.f;
  for (int i = lane; i < Bn; i += 64) {
    float gp = 0.f;
#pragma unroll
    for (int p = 0; p < GP; ++p) gp += gold_part[i * GP + p];
    acc += fscore[i] - gp;
  }
#pragma unroll
  for (int msk = 32; msk >= 1; msk >>= 1) acc += __shfl_xor(acc, msk);
  if (lane == 0) out[0] = acc * (1.0f / (float)Bn);
}

extern "C" void kernel_launch(void* const* d_in, const int* in_sizes, int n_in,
                              void* d_out, int out_size, void* d_ws, size_t ws_size,
                              hipStream_t stream) {
  const float* feats = (const float*)d_in[0];
  const float* trans = (const float*)d_in[1];
  const int* tags = (const int*)d_in[2];
  const int* lens = (const int*)d_in[3];

  float* fscore = (float*)d_ws;                    // [Bn]
  float* gold_part = fscore + Bn;                  // [Bn*GP]
  float* poffs = gold_part + (size_t)Bn * GP;      // [Bn*NC]
  float* pmats = poffs + (size_t)Bn * NC;          // [Bn*NC*1024]
  const size_t need =
      ((size_t)Bn + (size_t)Bn * GP + (size_t)Bn * NC +
       (size_t)Bn * NC * Kn * Kn) * sizeof(float);
  if (ws_size >= need) {
    crf_fused<<<MMB + GB, 256, 0, stream>>>(feats, trans, tags, lens, pmats,
                                            poffs, gold_part);
    crf_apply<<<Bn, 64, 0, stream>>>(trans, lens, pmats, poffs, fscore);
  } else {
    crf_main<<<2 * Bn, 64, 0, stream>>>(feats, trans, tags, lens, fscore,
                                        gold_part);
  }
  crf_reduce<<<1, 64, 0, stream>>>(fscore, gold_part, (float*)d_out);
}